// Round 7
// baseline (73.549 us; speedup 1.0000x reference)
//
#include <hip/hip_runtime.h>
#include <stdint.h>

#define NB    1024
#define IL    4096
#define NOUT  4096
#define FI    128
#define BTILE 8      // batches per block (bf16-packed -> 16B per input row)
#define OSPLIT 4
#define OTILE (NOUT / OSPLIT)        // 1024 outputs per block
#define SLAB_DW (IL * (BTILE / 2))   // 16384 dwords = 64KB per batch-group slab
#define SLAB_BLOCKS ((NB / BTILE) * IL / 256)   // 2048
#define SORT_BLOCKS (NOUT / 4)                  // 1024 (4 waves/block, 1 o per wave)

// round-to-nearest-even bf16, returned in the HIGH 16 bits (low 16 zeroed)
__device__ __forceinline__ uint32_t rne_bf16_hi(float x) {
  uint32_t u = __float_as_uint(x);
  u += 0x7FFFu + ((u >> 16) & 1u);
  return u & 0xFFFF0000u;
}

// ---------------- merged pre-pass ----------------
// bid <  SLAB_BLOCKS : build bf16 slab  slab[g][i*4+d] = bf16(in[8g+2d+1][i])<<16 | bf16(in[8g+2d][i])
// bid >= SLAB_BLOCKS : per-o pack words (bf16(w)<<16 | idx<<4), counting-sorted by
//                      bank group (idx&7) and cyclically rotated by 2*(o&63) so that
//                      the 64 lanes of a main-kernel wave sample evenly-spaced sorted
//                      positions -> ~8 lanes per 4-bank group instead of E[max]~13.
__global__ __launch_bounds__(256)
void prep_kernel(const float* __restrict__ in, uint32_t* __restrict__ slab,
                 const int* __restrict__ idx, const float* __restrict__ w,
                 uint32_t* __restrict__ pack) {
  const int bid = blockIdx.x;
  if (bid < SLAB_BLOCKS) {
    int t = bid * 256 + threadIdx.x;   // t = g*IL + i
    int g = t >> 12;
    int i = t & (IL - 1);
    const float* base = in + (size_t)g * (8 * IL) + i;
    uint4 v;
    v.x = rne_bf16_hi(base[1 * IL]) | (rne_bf16_hi(base[0 * IL]) >> 16);
    v.y = rne_bf16_hi(base[3 * IL]) | (rne_bf16_hi(base[2 * IL]) >> 16);
    v.z = rne_bf16_hi(base[5 * IL]) | (rne_bf16_hi(base[4 * IL]) >> 16);
    v.w = rne_bf16_hi(base[7 * IL]) | (rne_bf16_hi(base[6 * IL]) >> 16);
    reinterpret_cast<uint4*>(slab)[t] = v;
  } else {
    // wave-per-o fused pack + counting sort (key = idx&7) + rotate
    const int o    = (bid - SLAB_BLOCKS) * 4 + (threadIdx.x >> 6);
    const unsigned lane = threadIdx.x & 63u;
    const float* wrow = w   + (size_t)o * FI;
    const int*   irow = idx + (size_t)o * FI;
    uint32_t p0 = rne_bf16_hi(wrow[lane])      | (((uint32_t)irow[lane]      << 4) & 0xFFFFu);
    uint32_t p1 = rne_bf16_hi(wrow[64 + lane]) | (((uint32_t)irow[64 + lane] << 4) & 0xFFFFu);
    uint32_t k0 = (p0 >> 4) & 7u, k1 = (p1 >> 4) & 7u;
    uint64_t lt = (lane == 63u) ? 0x7FFFFFFFFFFFFFFFull : ((1ull << (lane + 1)) - 1) >> 1;
    uint32_t run = 0, base0 = 0, base1 = 0, c0k1 = 0;
    uint64_t match0 = 0, match1 = 0;
    #pragma unroll
    for (int k = 0; k < 8; ++k) {
      uint64_t b0 = __ballot(k0 == (uint32_t)k);
      uint64_t b1 = __ballot(k1 == (uint32_t)k);
      if (k0 == (uint32_t)k) { base0 = run; match0 = b0; }
      if (k1 == (uint32_t)k) { base1 = run; match1 = b1; c0k1 = (uint32_t)__popcll(b0); }
      run += (uint32_t)__popcll(b0) + (uint32_t)__popcll(b1);
    }
    uint32_t pos0 = base0 + (uint32_t)__popcll(match0 & lt);
    uint32_t pos1 = base1 + c0k1 + (uint32_t)__popcll(match1 & lt);
    uint32_t rot  = 2u * (uint32_t)(o & 63);
    pack[(size_t)o * FI + ((pos0 + rot) & 127u)] = p0;
    pack[(size_t)o * FI + ((pos1 + rot) & 127u)] = p1;
  }
}

// MODE 2: slab DMA staging + sorted pack   MODE 1: sorted pack, in-kernel staging
// MODE 0: raw inputs only (no workspace)
template<int MODE>
__global__ __launch_bounds__(1024)
void lincond_kernel(const float* __restrict__ input,
                    const uint32_t* __restrict__ slab,
                    const uint32_t* __restrict__ pack,
                    const int*  __restrict__ idxs,
                    const float* __restrict__ wgt,
                    const float* __restrict__ bias,
                    float* __restrict__ out) {
  __shared__ uint32_t lds[SLAB_DW];   // 64 KB: row i = 16B = 8 batches bf16
  const int bid   = blockIdx.x;
  const int b0    = (bid >> 2) * BTILE;
  const int obase = (bid & 3) * OTILE;
  const int tid   = threadIdx.x;

  if (MODE == 2) {
    // linear 64KB DMA: global -> LDS, 16B/lane, no VGPR roundtrip
    const uint32_t* src = slab + (size_t)(b0 >> 3) * SLAB_DW;
    #pragma unroll
    for (int r = 0; r < 4; ++r) {
      int e = (r * 1024 + tid) * 4;   // dword index, 16B-aligned
      __builtin_amdgcn_global_load_lds(
          (const __attribute__((address_space(1))) uint32_t*)(src + e),
          (__attribute__((address_space(3))) uint32_t*)(lds + e),
          16, 0, 0);
    }
  } else {
    #pragma unroll
    for (int rep = 0; rep < 16; ++rep) {
      int e = rep * 1024 + tid;
      int d = e >> 12;          // 0..3 (batch pair)
      int i = e & (IL - 1);     // 0..4095
      float x0 = input[(size_t)(b0 + 2 * d)     * IL + i];
      float x1 = input[(size_t)(b0 + 2 * d + 1) * IL + i];
      lds[i * 4 + d] = rne_bf16_hi(x1) | (rne_bf16_hi(x0) >> 16);
    }
  }
  __syncthreads();

  const int o = obase + tid;          // one output per thread
  const char* ldsb = reinterpret_cast<const char*>(lds);
  float acc[8] = {0.f,0.f,0.f,0.f,0.f,0.f,0.f,0.f};

// OFF = byte offset of a 16B row; WV = f32 weight (may carry garbage low bits, <2^-8 rel)
// hi-half batches use the dword directly: low 16 garbage bits are <2^-8 relative.
#define GBODY(OFF, WV) {                                          \
    uint4 g = *reinterpret_cast<const uint4*>(ldsb + (OFF));      \
    float wv = (WV);                                              \
    acc[0] = fmaf(wv, __uint_as_float(g.x << 16), acc[0]);        \
    acc[1] = fmaf(wv, __uint_as_float(g.x),       acc[1]);        \
    acc[2] = fmaf(wv, __uint_as_float(g.y << 16), acc[2]);        \
    acc[3] = fmaf(wv, __uint_as_float(g.y),       acc[3]);        \
    acc[4] = fmaf(wv, __uint_as_float(g.z << 16), acc[4]);        \
    acc[5] = fmaf(wv, __uint_as_float(g.z),       acc[5]);        \
    acc[6] = fmaf(wv, __uint_as_float(g.w << 16), acc[6]);        \
    acc[7] = fmaf(wv, __uint_as_float(g.w),       acc[7]);}

#define PBODY(P) \
    GBODY((P.x & 0xFFFFu), __uint_as_float(P.x)) \
    GBODY((P.y & 0xFFFFu), __uint_as_float(P.y)) \
    GBODY((P.z & 0xFFFFu), __uint_as_float(P.z)) \
    GBODY((P.w & 0xFFFFu), __uint_as_float(P.w))

#define RBODY(IV, WV) \
    GBODY(((uint32_t)IV.x << 4), WV.x) \
    GBODY(((uint32_t)IV.y << 4), WV.y) \
    GBODY(((uint32_t)IV.z << 4), WV.z) \
    GBODY(((uint32_t)IV.w << 4), WV.w)

  if (MODE >= 1) {
    const uint4* pw = reinterpret_cast<const uint4*>(pack) + (size_t)o * (FI / 4);
    #pragma unroll 2
    for (int j = 0; j < 8; ++j) {
      uint4 p0 = pw[j * 4 + 0];
      uint4 p1 = pw[j * 4 + 1];
      uint4 p2 = pw[j * 4 + 2];
      uint4 p3 = pw[j * 4 + 3];
      PBODY(p0) PBODY(p1) PBODY(p2) PBODY(p3)
    }
  } else {
    const int4*   ip = reinterpret_cast<const int4*>(idxs)  + (size_t)o * (FI / 4);
    const float4* wp = reinterpret_cast<const float4*>(wgt) + (size_t)o * (FI / 4);
    #pragma unroll 2
    for (int j = 0; j < 8; ++j) {
      int4   i0 = ip[j * 4 + 0], i1 = ip[j * 4 + 1], i2 = ip[j * 4 + 2], i3 = ip[j * 4 + 3];
      float4 w0 = wp[j * 4 + 0], w1 = wp[j * 4 + 1], w2 = wp[j * 4 + 2], w3 = wp[j * 4 + 3];
      RBODY(i0, w0) RBODY(i1, w1) RBODY(i2, w2) RBODY(i3, w3)
    }
  }

  const float bv = bias[o];
  #pragma unroll
  for (int k = 0; k < 8; ++k) {
    out[(size_t)(b0 + k) * NOUT + o] = acc[k] + bv;   // coalesced: lanes -> consecutive o
  }
}

extern "C" void kernel_launch(void* const* d_in, const int* in_sizes, int n_in,
                              void* d_out, int out_size, void* d_ws, size_t ws_size,
                              hipStream_t stream) {
  const float* input  = (const float*)d_in[0];
  const float* weight = (const float*)d_in[1];
  const float* bias   = (const float*)d_in[2];
  const int*   idxs   = (const int*)d_in[3];
  float*       out    = (float*)d_out;

  const size_t pack_bytes = (size_t)NOUT * FI * sizeof(uint32_t);              // 2 MB
  const size_t slab_bytes = (size_t)(NB / BTILE) * SLAB_DW * sizeof(uint32_t); // 8 MB
  const int grid = (NB / BTILE) * OSPLIT;                                      // 512 blocks

  if (ws_size >= pack_bytes + slab_bytes) {
    uint32_t* pack = (uint32_t*)d_ws;
    uint32_t* slab = (uint32_t*)((char*)d_ws + pack_bytes);
    prep_kernel<<<SLAB_BLOCKS + SORT_BLOCKS, 256, 0, stream>>>(input, slab, idxs, weight, pack);
    lincond_kernel<2><<<grid, 1024, 0, stream>>>(input, slab, pack, nullptr, nullptr, bias, out);
  } else {
    lincond_kernel<0><<<grid, 1024, 0, stream>>>(input, nullptr, nullptr, idxs, weight, bias, out);
  }
}

// Round 8
// 54.312 us; speedup vs baseline: 1.3542x; 1.3542x over previous
//
#include <hip/hip_runtime.h>
#include <stdint.h>

#define NB    1024
#define IL    4096
#define NOUT  4096
#define FI    128
#define BTILE 8      // batches per block (bf16-packed -> 16B per input row)
#define OSPLIT 4
#define OTILE (NOUT / OSPLIT)        // 1024 outputs per block
#define SLAB_DW (IL * (BTILE / 2))   // 16384 dwords = 64KB per batch-group slab
#define SLAB_BLOCKS ((NB / BTILE) * IL / 256)   // 2048
#define PACK_BLOCKS (NOUT * FI / (256 * 4))     // 512 (uint4 per thread, linear)

// round-to-nearest-even bf16, returned in the HIGH 16 bits (low 16 zeroed)
__device__ __forceinline__ uint32_t rne_bf16_hi(float x) {
  uint32_t u = __float_as_uint(x);
  u += 0x7FFFu + ((u >> 16) & 1u);
  return u & 0xFFFF0000u;
}

// ---------------- merged pre-pass (one launch) ----------------
// bid <  SLAB_BLOCKS : bf16 slab  slab[g][i*4+d] = bf16(in[8g+2d+1][i])<<16 | bf16(in[8g+2d][i])
// bid >= SLAB_BLOCKS : pack[o*FI+f] = (bf16(w)<<16) | (idx<<4)  -- PLAIN order,
//                      coalesced uint4 writes (no sort: R7's sort raised conflicts +45%)
__global__ __launch_bounds__(256)
void prep_kernel(const float* __restrict__ in, uint32_t* __restrict__ slab,
                 const int* __restrict__ idx, const float* __restrict__ w,
                 uint32_t* __restrict__ pack) {
  const int bid = blockIdx.x;
  if (bid < SLAB_BLOCKS) {
    int t = bid * 256 + threadIdx.x;   // t = g*IL + i
    int g = t >> 12;
    int i = t & (IL - 1);
    const float* base = in + (size_t)g * (8 * IL) + i;
    uint4 v;
    v.x = rne_bf16_hi(base[1 * IL]) | (rne_bf16_hi(base[0 * IL]) >> 16);
    v.y = rne_bf16_hi(base[3 * IL]) | (rne_bf16_hi(base[2 * IL]) >> 16);
    v.z = rne_bf16_hi(base[5 * IL]) | (rne_bf16_hi(base[4 * IL]) >> 16);
    v.w = rne_bf16_hi(base[7 * IL]) | (rne_bf16_hi(base[6 * IL]) >> 16);
    reinterpret_cast<uint4*>(slab)[t] = v;
  } else {
    int t = (bid - SLAB_BLOCKS) * 256 + threadIdx.x;   // uint4 element index
    int4   iv = reinterpret_cast<const int4*>(idx)[t];
    float4 wv = reinterpret_cast<const float4*>(w)[t];
    uint4 p;
    p.x = rne_bf16_hi(wv.x) | (((uint32_t)iv.x << 4) & 0xFFFFu);
    p.y = rne_bf16_hi(wv.y) | (((uint32_t)iv.y << 4) & 0xFFFFu);
    p.z = rne_bf16_hi(wv.z) | (((uint32_t)iv.z << 4) & 0xFFFFu);
    p.w = rne_bf16_hi(wv.w) | (((uint32_t)iv.w << 4) & 0xFFFFu);
    reinterpret_cast<uint4*>(pack)[t] = p;
  }
}

// MODE 2: slab DMA staging + pack table   MODE 0: raw inputs only (no workspace)
template<int MODE>
__global__ __launch_bounds__(1024)
void lincond_kernel(const float* __restrict__ input,
                    const uint32_t* __restrict__ slab,
                    const uint32_t* __restrict__ pack,
                    const int*  __restrict__ idxs,
                    const float* __restrict__ wgt,
                    const float* __restrict__ bias,
                    float* __restrict__ out) {
  __shared__ uint32_t lds[SLAB_DW];   // 64 KB: row i = 16B = 8 batches bf16
  const int bid   = blockIdx.x;
  const int b0    = (bid >> 2) * BTILE;
  const int obase = (bid & 3) * OTILE;
  const int tid   = threadIdx.x;

  if (MODE == 2) {
    // linear 64KB DMA: global -> LDS, 16B/lane, no VGPR roundtrip
    const uint32_t* src = slab + (size_t)(b0 >> 3) * SLAB_DW;
    #pragma unroll
    for (int r = 0; r < 4; ++r) {
      int e = (r * 1024 + tid) * 4;   // dword index, 16B-aligned
      __builtin_amdgcn_global_load_lds(
          (const __attribute__((address_space(1))) uint32_t*)(src + e),
          (__attribute__((address_space(3))) uint32_t*)(lds + e),
          16, 0, 0);
    }
  } else {
    #pragma unroll
    for (int rep = 0; rep < 16; ++rep) {
      int e = rep * 1024 + tid;
      int d = e >> 12;          // 0..3 (batch pair)
      int i = e & (IL - 1);     // 0..4095
      float x0 = input[(size_t)(b0 + 2 * d)     * IL + i];
      float x1 = input[(size_t)(b0 + 2 * d + 1) * IL + i];
      lds[i * 4 + d] = rne_bf16_hi(x1) | (rne_bf16_hi(x0) >> 16);
    }
  }
  __syncthreads();

  const int o = obase + tid;          // one output per thread
  const char* ldsb = reinterpret_cast<const char*>(lds);
  float acc[8] = {0.f,0.f,0.f,0.f,0.f,0.f,0.f,0.f};

// OFF = byte offset of a 16B row; WV = f32 weight (clean, masked)
#define GBODY(OFF, WV) {                                          \
    uint4 g = *reinterpret_cast<const uint4*>(ldsb + (OFF));      \
    float wv = (WV);                                              \
    acc[0] = fmaf(wv, __uint_as_float(g.x << 16),         acc[0]);\
    acc[1] = fmaf(wv, __uint_as_float(g.x & 0xFFFF0000u), acc[1]);\
    acc[2] = fmaf(wv, __uint_as_float(g.y << 16),         acc[2]);\
    acc[3] = fmaf(wv, __uint_as_float(g.y & 0xFFFF0000u), acc[3]);\
    acc[4] = fmaf(wv, __uint_as_float(g.z << 16),         acc[4]);\
    acc[5] = fmaf(wv, __uint_as_float(g.z & 0xFFFF0000u), acc[5]);\
    acc[6] = fmaf(wv, __uint_as_float(g.w << 16),         acc[6]);\
    acc[7] = fmaf(wv, __uint_as_float(g.w & 0xFFFF0000u), acc[7]);}

#define PBODY(P) \
    GBODY((P.x & 0xFFFFu), __uint_as_float(P.x & 0xFFFF0000u)) \
    GBODY((P.y & 0xFFFFu), __uint_as_float(P.y & 0xFFFF0000u)) \
    GBODY((P.z & 0xFFFFu), __uint_as_float(P.z & 0xFFFF0000u)) \
    GBODY((P.w & 0xFFFFu), __uint_as_float(P.w & 0xFFFF0000u))

#define RBODY(IV, WV) \
    GBODY(((uint32_t)IV.x << 4), WV.x) \
    GBODY(((uint32_t)IV.y << 4), WV.y) \
    GBODY(((uint32_t)IV.z << 4), WV.z) \
    GBODY(((uint32_t)IV.w << 4), WV.w)

  if (MODE >= 1) {
    const uint4* pw = reinterpret_cast<const uint4*>(pack) + (size_t)o * (FI / 4);
    #pragma unroll 2
    for (int j = 0; j < 8; ++j) {
      uint4 p0 = pw[j * 4 + 0];
      uint4 p1 = pw[j * 4 + 1];
      uint4 p2 = pw[j * 4 + 2];
      uint4 p3 = pw[j * 4 + 3];
      PBODY(p0) PBODY(p1) PBODY(p2) PBODY(p3)
    }
  } else {
    const int4*   ip = reinterpret_cast<const int4*>(idxs)  + (size_t)o * (FI / 4);
    const float4* wp = reinterpret_cast<const float4*>(wgt) + (size_t)o * (FI / 4);
    #pragma unroll 2
    for (int j = 0; j < 8; ++j) {
      int4   i0 = ip[j * 4 + 0], i1 = ip[j * 4 + 1], i2 = ip[j * 4 + 2], i3 = ip[j * 4 + 3];
      float4 w0 = wp[j * 4 + 0], w1 = wp[j * 4 + 1], w2 = wp[j * 4 + 2], w3 = wp[j * 4 + 3];
      RBODY(i0, w0) RBODY(i1, w1) RBODY(i2, w2) RBODY(i3, w3)
    }
  }

  const float bv = bias[o];
  #pragma unroll
  for (int k = 0; k < 8; ++k) {
    out[(size_t)(b0 + k) * NOUT + o] = acc[k] + bv;   // coalesced: lanes -> consecutive o
  }
}

extern "C" void kernel_launch(void* const* d_in, const int* in_sizes, int n_in,
                              void* d_out, int out_size, void* d_ws, size_t ws_size,
                              hipStream_t stream) {
  const float* input  = (const float*)d_in[0];
  const float* weight = (const float*)d_in[1];
  const float* bias   = (const float*)d_in[2];
  const int*   idxs   = (const int*)d_in[3];
  float*       out    = (float*)d_out;

  const size_t pack_bytes = (size_t)NOUT * FI * sizeof(uint32_t);              // 2 MB
  const size_t slab_bytes = (size_t)(NB / BTILE) * SLAB_DW * sizeof(uint32_t); // 8 MB
  const int grid = (NB / BTILE) * OSPLIT;                                      // 512 blocks

  if (ws_size >= pack_bytes + slab_bytes) {
    uint32_t* pack = (uint32_t*)d_ws;
    uint32_t* slab = (uint32_t*)((char*)d_ws + pack_bytes);
    prep_kernel<<<SLAB_BLOCKS + PACK_BLOCKS, 256, 0, stream>>>(input, slab, idxs, weight, pack);
    lincond_kernel<2><<<grid, 1024, 0, stream>>>(input, slab, pack, nullptr, nullptr, bias, out);
  } else {
    lincond_kernel<0><<<grid, 1024, 0, stream>>>(input, nullptr, nullptr, idxs, weight, bias, out);
  }
}